// Round 1
// baseline (37.483 us; speedup 1.0000x reference)
//
#include <hip/hip_runtime.h>

#define BATCH   8192
#define FBINS   2048
#define KSLOTS  6

#define HBLOCKS 2048
#define HTHREADS 256
#define RTHREADS 256
#define RBLOCKS (BATCH / RTHREADS)   // 32

#define LS   0.1f
#define LBW  0.05f
#define BWMAX 4.0f
#define LAP  0.5f
#define LPK  0.3f
#define LUM  0.1f

// ---------------- Kernel 1: Huber partial sums (the only heavy part) ----------------
__global__ __launch_bounds__(HTHREADS) void huber_partial(
    const float* __restrict__ pred, const float* __restrict__ tgt,
    float* __restrict__ partial)
{
    const long long N4 = (long long)BATCH * FBINS / 4;
    long long tid = (long long)blockIdx.x * blockDim.x + threadIdx.x;
    long long stride = (long long)gridDim.x * blockDim.x;
    const float4* __restrict__ p4 = (const float4*)pred;
    const float4* __restrict__ t4 = (const float4*)tgt;

    float s = 0.f;
    for (long long i = tid; i < N4; i += stride) {
        float4 a = p4[i];
        float4 b = t4[i];
        {
            float e = a.x - b.x; float ab = fabsf(e);
            s += (ab < 1.f) ? 0.5f * e * e : ab - 0.5f;
        }
        {
            float e = a.y - b.y; float ab = fabsf(e);
            s += (ab < 1.f) ? 0.5f * e * e : ab - 0.5f;
        }
        {
            float e = a.z - b.z; float ab = fabsf(e);
            s += (ab < 1.f) ? 0.5f * e * e : ab - 0.5f;
        }
        {
            float e = a.w - b.w; float ab = fabsf(e);
            s += (ab < 1.f) ? 0.5f * e * e : ab - 0.5f;
        }
    }

    __shared__ float sm[HTHREADS];
    sm[threadIdx.x] = s;
    __syncthreads();
    for (int o = HTHREADS / 2; o > 0; o >>= 1) {
        if (threadIdx.x < o) sm[threadIdx.x] += sm[threadIdx.x + o];
        __syncthreads();
    }
    if (threadIdx.x == 0) partial[blockIdx.x] = sm[0];
}

// ---------------- Kernel 2: per-row greedy matching + small sums ----------------
// partial layout: partial[7 * blockIdx + c], c in:
//   0 amps_sum, 1 bw_sum, 2 ap_sum, 3 peaks_sum, 4 mask_sum, 5 um_cnt, 6 um_amps
__global__ __launch_bounds__(RTHREADS) void row_partial(
    const float* __restrict__ cfs,   const float* __restrict__ amps,
    const float* __restrict__ bws,   const float* __restrict__ expn,
    const float* __restrict__ offs,  const float* __restrict__ gt_cfs,
    const float* __restrict__ gt_amps, const float* __restrict__ gt_bws,
    const float* __restrict__ gt_off, const float* __restrict__ gt_exp,
    const float* __restrict__ mask,  float* __restrict__ partial)
{
    int b = blockIdx.x * blockDim.x + threadIdx.x;

    float amps_sum = 0.f, bw_sum = 0.f, ap_sum = 0.f, peaks_sum = 0.f;
    float mask_sum = 0.f, um_cnt = 0.f, um_amps = 0.f;

    if (b < BATCH) {
        float c[KSLOTS], a[KSLOTS], w[KSLOTS];
        float gc[KSLOTS], ga[KSLOTS], gw[KSLOTS], m[KSLOTS];
        #pragma unroll
        for (int i = 0; i < KSLOTS; i++) {
            c[i]  = cfs[b * KSLOTS + i];
            a[i]  = amps[b * KSLOTS + i];
            w[i]  = bws[b * KSLOTS + i];
            gc[i] = gt_cfs[b * KSLOTS + i];
            ga[i] = gt_amps[b * KSLOTS + i];
            gw[i] = gt_bws[b * KSLOTS + i];
            m[i]  = mask[b * KSLOTS + i];
        }

        bool used[KSLOTS];
        #pragma unroll
        for (int i = 0; i < KSLOTS; i++) used[i] = false;

        // Sequential greedy over GT slots (matches jax.lax.scan order).
        // jnp.argmin tie-break = first index; strict < preserves that.
        for (int j = 0; j < KSLOTS; j++) {
            if (m[j] > 0.5f) {
                int best = -1;
                float bd = 3.402823e+38f;
                #pragma unroll
                for (int i = 0; i < KSLOTS; i++) {
                    if (!used[i]) {
                        float d = fabsf(gc[j] - c[i]);
                        if (d < bd) { bd = d; best = i; }
                    }
                }
                used[best] = true;
                float dc = c[best] - gc[j];
                float da = a[best] - ga[j];
                float dw = w[best] - gw[j];
                peaks_sum += dc * dc + da * da + dw * dw;
                mask_sum  += 1.f;
            }
        }

        #pragma unroll
        for (int i = 0; i < KSLOTS; i++) {
            amps_sum += a[i];
            float ex = fmaxf(w[i] - BWMAX, 0.f);
            bw_sum += ex * ex;
            if (!used[i]) { um_cnt += 1.f; um_amps += a[i]; }
        }

        float de = expn[b] - gt_exp[b];
        float dof = offs[b] - gt_off[b];
        ap_sum = de * de + dof * dof;
    }

    __shared__ float sm[7][RTHREADS];
    sm[0][threadIdx.x] = amps_sum;
    sm[1][threadIdx.x] = bw_sum;
    sm[2][threadIdx.x] = ap_sum;
    sm[3][threadIdx.x] = peaks_sum;
    sm[4][threadIdx.x] = mask_sum;
    sm[5][threadIdx.x] = um_cnt;
    sm[6][threadIdx.x] = um_amps;
    __syncthreads();
    for (int o = RTHREADS / 2; o > 0; o >>= 1) {
        if (threadIdx.x < o) {
            #pragma unroll
            for (int cidx = 0; cidx < 7; cidx++)
                sm[cidx][threadIdx.x] += sm[cidx][threadIdx.x + o];
        }
        __syncthreads();
    }
    if (threadIdx.x < 7) partial[7 * blockIdx.x + threadIdx.x] = sm[threadIdx.x][0];
}

// ---------------- Kernel 3: finalize ----------------
__global__ __launch_bounds__(256) void finalize(
    const float* __restrict__ hpart, const float* __restrict__ rpart,
    float* __restrict__ out)
{
    __shared__ double sm[256];
    double s = 0.0;
    for (int i = threadIdx.x; i < HBLOCKS; i += 256) s += (double)hpart[i];
    sm[threadIdx.x] = s;
    __syncthreads();
    for (int o = 128; o > 0; o >>= 1) {
        if (threadIdx.x < o) sm[threadIdx.x] += sm[threadIdx.x + o];
        __syncthreads();
    }

    if (threadIdx.x == 0) {
        double huber_total = sm[0];
        double acc[7];
        for (int c = 0; c < 7; c++) acc[c] = 0.0;
        for (int blk = 0; blk < RBLOCKS; blk++)
            for (int c = 0; c < 7; c++)
                acc[c] += (double)rpart[7 * blk + c];

        double amps_sum  = acc[0];
        double bw_sum    = acc[1];
        double ap_sum    = acc[2];
        double peaks_sum = acc[3];
        double mask_sum  = acc[4];
        double um_cnt    = acc[5];
        double um_amps   = acc[6];

        double l_recon  = huber_total / ((double)BATCH * FBINS);
        double l_sparse = amps_sum / ((double)BATCH * KSLOTS);
        double l_bw     = bw_sum / ((double)BATCH * KSLOTS);
        double l_ap     = ap_sum / (double)BATCH;
        double n_real   = mask_sum > 1.0 ? mask_sum : 1.0;
        double l_peaks  = peaks_sum / n_real;
        double n_um     = um_cnt > 1.0 ? um_cnt : 1.0;
        double l_um     = um_amps / n_um;

        double total = l_recon + (double)LS * l_sparse + (double)LBW * l_bw
                     + (double)LAP * l_ap + (double)LPK * l_peaks + (double)LUM * l_um;
        out[0] = (float)total;
    }
}

extern "C" void kernel_launch(void* const* d_in, const int* in_sizes, int n_in,
                              void* d_out, int out_size, void* d_ws, size_t ws_size,
                              hipStream_t stream) {
    const float* pred_psd = (const float*)d_in[0];
    const float* true_psd = (const float*)d_in[1];
    const float* cfs      = (const float*)d_in[2];
    const float* amps     = (const float*)d_in[3];
    const float* bws      = (const float*)d_in[4];
    const float* expn     = (const float*)d_in[5];
    const float* offs     = (const float*)d_in[6];
    const float* gt_cfs   = (const float*)d_in[7];
    const float* gt_amps  = (const float*)d_in[8];
    const float* gt_bws   = (const float*)d_in[9];
    const float* gt_off   = (const float*)d_in[10];
    const float* gt_exp   = (const float*)d_in[11];
    const float* mask     = (const float*)d_in[12];
    float* out = (float*)d_out;

    float* hpart = (float*)d_ws;                 // HBLOCKS floats
    float* rpart = hpart + HBLOCKS;              // RBLOCKS*7 floats

    huber_partial<<<HBLOCKS, HTHREADS, 0, stream>>>(pred_psd, true_psd, hpart);
    row_partial<<<RBLOCKS, RTHREADS, 0, stream>>>(cfs, amps, bws, expn, offs,
                                                  gt_cfs, gt_amps, gt_bws,
                                                  gt_off, gt_exp, mask, rpart);
    finalize<<<1, 256, 0, stream>>>(hpart, rpart, out);
}

// Round 2
// 36.861 us; speedup vs baseline: 1.0169x; 1.0169x over previous
//
#include <hip/hip_runtime.h>

#define BATCH   8192
#define FBINS   2048
#define KSLOTS  6

#define HBLOCKS 2048
#define HTHREADS 256
#define HSTRIDE (HBLOCKS * HTHREADS)               // 524288
#define N4_TOTAL ((long long)BATCH * FBINS / 4)    // 4194304
#define HITERS  8                                   // N4_TOTAL / HSTRIDE

#define RTHREADS 256
#define RBLOCKS (BATCH / RTHREADS)   // 32

#define LS   0.1f
#define LBW  0.05f
#define BWMAX 4.0f
#define LAP  0.5f
#define LPK  0.3f
#define LUM  0.1f

__device__ __forceinline__ float huber4(float4 a, float4 b) {
    float s = 0.f;
    {
        float e = a.x - b.x; float ab = fabsf(e);
        s += (ab < 1.f) ? 0.5f * e * e : ab - 0.5f;
    }
    {
        float e = a.y - b.y; float ab = fabsf(e);
        s += (ab < 1.f) ? 0.5f * e * e : ab - 0.5f;
    }
    {
        float e = a.z - b.z; float ab = fabsf(e);
        s += (ab < 1.f) ? 0.5f * e * e : ab - 0.5f;
    }
    {
        float e = a.w - b.w; float ab = fabsf(e);
        s += (ab < 1.f) ? 0.5f * e * e : ab - 0.5f;
    }
    return s;
}

// ---------------- Kernel 1: Huber partial sums (the only heavy part) ----------------
// Compile-time trip count (8) with full preload: 16 outstanding float4 loads
// per thread for memory-level parallelism. VGPR ~80 -> 4 waves/SIMD, fine.
__global__ __launch_bounds__(HTHREADS) void huber_partial(
    const float* __restrict__ pred, const float* __restrict__ tgt,
    float* __restrict__ partial)
{
    const long long tid = (long long)blockIdx.x * HTHREADS + threadIdx.x;
    const float4* __restrict__ p4 = (const float4*)pred;
    const float4* __restrict__ t4 = (const float4*)tgt;

    float4 a[HITERS], b[HITERS];
    #pragma unroll
    for (int it = 0; it < HITERS; it++)
        a[it] = p4[tid + (long long)it * HSTRIDE];
    #pragma unroll
    for (int it = 0; it < HITERS; it++)
        b[it] = t4[tid + (long long)it * HSTRIDE];

    float s = 0.f;
    #pragma unroll
    for (int it = 0; it < HITERS; it++)
        s += huber4(a[it], b[it]);

    // wave64 shuffle reduction, then cross-wave via LDS
    #pragma unroll
    for (int o = 32; o > 0; o >>= 1)
        s += __shfl_down(s, o, 64);

    __shared__ float sm[HTHREADS / 64];
    int wave = threadIdx.x >> 6;
    int lane = threadIdx.x & 63;
    if (lane == 0) sm[wave] = s;
    __syncthreads();
    if (threadIdx.x == 0) {
        float t = sm[0] + sm[1] + sm[2] + sm[3];
        partial[blockIdx.x] = t;
    }
}

// ---------------- Kernel 2: per-row greedy matching + small sums ----------------
// partial layout: partial[7 * blockIdx + c], c in:
//   0 amps_sum, 1 bw_sum, 2 ap_sum, 3 peaks_sum, 4 mask_sum, 5 um_cnt, 6 um_amps
__global__ __launch_bounds__(RTHREADS) void row_partial(
    const float* __restrict__ cfs,   const float* __restrict__ amps,
    const float* __restrict__ bws,   const float* __restrict__ expn,
    const float* __restrict__ offs,  const float* __restrict__ gt_cfs,
    const float* __restrict__ gt_amps, const float* __restrict__ gt_bws,
    const float* __restrict__ gt_off, const float* __restrict__ gt_exp,
    const float* __restrict__ mask,  float* __restrict__ partial)
{
    int b = blockIdx.x * blockDim.x + threadIdx.x;

    float amps_sum = 0.f, bw_sum = 0.f, ap_sum = 0.f, peaks_sum = 0.f;
    float mask_sum = 0.f, um_cnt = 0.f, um_amps = 0.f;

    if (b < BATCH) {
        float c[KSLOTS], a[KSLOTS], w[KSLOTS];
        float gc[KSLOTS], ga[KSLOTS], gw[KSLOTS], m[KSLOTS];
        #pragma unroll
        for (int i = 0; i < KSLOTS; i++) {
            c[i]  = cfs[b * KSLOTS + i];
            a[i]  = amps[b * KSLOTS + i];
            w[i]  = bws[b * KSLOTS + i];
            gc[i] = gt_cfs[b * KSLOTS + i];
            ga[i] = gt_amps[b * KSLOTS + i];
            gw[i] = gt_bws[b * KSLOTS + i];
            m[i]  = mask[b * KSLOTS + i];
        }

        bool used[KSLOTS];
        #pragma unroll
        for (int i = 0; i < KSLOTS; i++) used[i] = false;

        // Sequential greedy over GT slots (matches jax.lax.scan order).
        // jnp.argmin tie-break = first index; strict < preserves that.
        for (int j = 0; j < KSLOTS; j++) {
            if (m[j] > 0.5f) {
                int best = -1;
                float bd = 3.402823e+38f;
                #pragma unroll
                for (int i = 0; i < KSLOTS; i++) {
                    if (!used[i]) {
                        float d = fabsf(gc[j] - c[i]);
                        if (d < bd) { bd = d; best = i; }
                    }
                }
                used[best] = true;
                float dc = c[best] - gc[j];
                float da = a[best] - ga[j];
                float dw = w[best] - gw[j];
                peaks_sum += dc * dc + da * da + dw * dw;
                mask_sum  += 1.f;
            }
        }

        #pragma unroll
        for (int i = 0; i < KSLOTS; i++) {
            amps_sum += a[i];
            float ex = fmaxf(w[i] - BWMAX, 0.f);
            bw_sum += ex * ex;
            if (!used[i]) { um_cnt += 1.f; um_amps += a[i]; }
        }

        float de = expn[b] - gt_exp[b];
        float dof = offs[b] - gt_off[b];
        ap_sum = de * de + dof * dof;
    }

    __shared__ float sm[7][RTHREADS];
    sm[0][threadIdx.x] = amps_sum;
    sm[1][threadIdx.x] = bw_sum;
    sm[2][threadIdx.x] = ap_sum;
    sm[3][threadIdx.x] = peaks_sum;
    sm[4][threadIdx.x] = mask_sum;
    sm[5][threadIdx.x] = um_cnt;
    sm[6][threadIdx.x] = um_amps;
    __syncthreads();
    for (int o = RTHREADS / 2; o > 0; o >>= 1) {
        if (threadIdx.x < o) {
            #pragma unroll
            for (int cidx = 0; cidx < 7; cidx++)
                sm[cidx][threadIdx.x] += sm[cidx][threadIdx.x + o];
        }
        __syncthreads();
    }
    if (threadIdx.x < 7) partial[7 * blockIdx.x + threadIdx.x] = sm[threadIdx.x][0];
}

// ---------------- Kernel 3: finalize ----------------
__global__ __launch_bounds__(256) void finalize(
    const float* __restrict__ hpart, const float* __restrict__ rpart,
    float* __restrict__ out)
{
    __shared__ double sm[256];
    double s = 0.0;
    for (int i = threadIdx.x; i < HBLOCKS; i += 256) s += (double)hpart[i];
    sm[threadIdx.x] = s;
    __syncthreads();
    for (int o = 128; o > 0; o >>= 1) {
        if (threadIdx.x < o) sm[threadIdx.x] += sm[threadIdx.x + o];
        __syncthreads();
    }

    if (threadIdx.x == 0) {
        double huber_total = sm[0];
        double acc[7];
        for (int c = 0; c < 7; c++) acc[c] = 0.0;
        for (int blk = 0; blk < RBLOCKS; blk++)
            for (int c = 0; c < 7; c++)
                acc[c] += (double)rpart[7 * blk + c];

        double amps_sum  = acc[0];
        double bw_sum    = acc[1];
        double ap_sum    = acc[2];
        double peaks_sum = acc[3];
        double mask_sum  = acc[4];
        double um_cnt    = acc[5];
        double um_amps   = acc[6];

        double l_recon  = huber_total / ((double)BATCH * FBINS);
        double l_sparse = amps_sum / ((double)BATCH * KSLOTS);
        double l_bw     = bw_sum / ((double)BATCH * KSLOTS);
        double l_ap     = ap_sum / (double)BATCH;
        double n_real   = mask_sum > 1.0 ? mask_sum : 1.0;
        double l_peaks  = peaks_sum / n_real;
        double n_um     = um_cnt > 1.0 ? um_cnt : 1.0;
        double l_um     = um_amps / n_um;

        double total = l_recon + (double)LS * l_sparse + (double)LBW * l_bw
                     + (double)LAP * l_ap + (double)LPK * l_peaks + (double)LUM * l_um;
        out[0] = (float)total;
    }
}

extern "C" void kernel_launch(void* const* d_in, const int* in_sizes, int n_in,
                              void* d_out, int out_size, void* d_ws, size_t ws_size,
                              hipStream_t stream) {
    const float* pred_psd = (const float*)d_in[0];
    const float* true_psd = (const float*)d_in[1];
    const float* cfs      = (const float*)d_in[2];
    const float* amps     = (const float*)d_in[3];
    const float* bws      = (const float*)d_in[4];
    const float* expn     = (const float*)d_in[5];
    const float* offs     = (const float*)d_in[6];
    const float* gt_cfs   = (const float*)d_in[7];
    const float* gt_amps  = (const float*)d_in[8];
    const float* gt_bws   = (const float*)d_in[9];
    const float* gt_off   = (const float*)d_in[10];
    const float* gt_exp   = (const float*)d_in[11];
    const float* mask     = (const float*)d_in[12];
    float* out = (float*)d_out;

    float* hpart = (float*)d_ws;                 // HBLOCKS floats
    float* rpart = hpart + HBLOCKS;              // RBLOCKS*7 floats

    huber_partial<<<HBLOCKS, HTHREADS, 0, stream>>>(pred_psd, true_psd, hpart);
    row_partial<<<RBLOCKS, RTHREADS, 0, stream>>>(cfs, amps, bws, expn, offs,
                                                  gt_cfs, gt_amps, gt_bws,
                                                  gt_off, gt_exp, mask, rpart);
    finalize<<<1, 256, 0, stream>>>(hpart, rpart, out);
}